// Round 14
// baseline (202.718 us; speedup 1.0000x reference)
//
#include <hip/hip_runtime.h>

#define N_NODES 20000
#define N_EDGES 320000
#define NGRAPH  256
#define NTAC    1000
#define HD      512
#define NC      25          // K-chunks for the big GEMM (20000 = 25 * 800)
#define KCH     800

typedef __attribute__((ext_vector_type(8))) short bf16x8;
typedef __attribute__((ext_vector_type(4))) short short4v;
typedef __attribute__((ext_vector_type(4))) float f32x4;

__device__ __forceinline__ short f2bf(float f) {      // RNE float->bf16
  union { float f; unsigned u; } v; v.f = f;
  unsigned r = v.u + 0x7FFFu + ((v.u >> 16) & 1u);
  return (short)(r >> 16);
}
__device__ __forceinline__ float bf2f(short s) {
  union { unsigned u; float f; } v;
  v.u = ((unsigned)(unsigned short)s) << 16;
  return v.f;
}
__device__ __forceinline__ bf16x8 cast8(const float* p) {
  float4 v0 = *reinterpret_cast<const float4*>(p);
  float4 v1 = *reinterpret_cast<const float4*>(p + 4);
  bf16x8 o;
  o[0] = f2bf(v0.x); o[1] = f2bf(v0.y); o[2] = f2bf(v0.z); o[3] = f2bf(v0.w);
  o[4] = f2bf(v1.x); o[5] = f2bf(v1.y); o[6] = f2bf(v1.z); o[7] = f2bf(v1.w);
  return o;
}
__device__ __forceinline__ void gload16(const void* g, void* l) {
  __builtin_amdgcn_global_load_lds((const __attribute__((address_space(1))) void*)g,
                                   (__attribute__((address_space(3))) void*)l,
                                   16, 0, 0);
}

// ---- fused front: weight casts + embed + degree + gbounds + zero(COEF, PX) --
__global__ void k_front(const float* __restrict__ Wc1, const float* __restrict__ Wc2,
                        short* __restrict__ WC1B, short* __restrict__ WC2B,
                        const float* __restrict__ W1l, const float* __restrict__ W1r,
                        short* __restrict__ BC1,
                        const float* __restrict__ W2l, const float* __restrict__ W2r,
                        short* __restrict__ BC2,
                        const int* __restrict__ ntype, const int* __restrict__ ntac,
                        const float* __restrict__ temb, const float* __restrict__ tacemb,
                        short* __restrict__ A1,
                        const int* __restrict__ dst, int* __restrict__ deg,
                        const int* __restrict__ batch, int* __restrict__ rstart,
                        float* __restrict__ COEF, float* __restrict__ PX) {
  int idx = blockIdx.x * 256 + threadIdx.x;
  const int S0 = HD * HD / 8;          // Wc1 cast (oct)
  const int S1 = NTAC * HD / 8;        // Wc2 cast (oct)
  const int S2 = HD * 192 / 8;         // BC1 (oct)
  const int S3 = HD * 1024 / 8;        // BC2 (oct)
  const int S4 = N_NODES * 24;         // embed
  const int S5 = N_EDGES;              // degree
  const int S6 = N_NODES;              // gbounds
  const int S7 = NGRAPH * N_NODES / 4; // zero COEF fp32 (quad)
  const int S8 = NGRAPH * HD / 4;      // zero PX fp32 (quad)
  if (idx < S0) {
    *reinterpret_cast<bf16x8*>(&WC1B[idx * 8]) = cast8(&Wc1[idx * 8]);
  } else if ((idx -= S0) < S1) {
    *reinterpret_cast<bf16x8*>(&WC2B[idx * 8]) = cast8(&Wc2[idx * 8]);
  } else if ((idx -= S1) < S2) {
    int n = idx / 24, k8 = idx - n * 24;
    const float* s = (k8 < 12) ? &W1l[(size_t)n * 96 + k8 * 8]
                               : &W1r[(size_t)n * 96 + (k8 - 12) * 8];
    *reinterpret_cast<bf16x8*>(&BC1[(size_t)n * 192 + k8 * 8]) = cast8(s);
  } else if ((idx -= S2) < S3) {
    int n = idx >> 7, k8 = idx & 127;
    const float* s = (k8 < 64) ? &W2l[(size_t)n * 512 + k8 * 8]
                               : &W2r[(size_t)n * 512 + (k8 - 64) * 8];
    *reinterpret_cast<bf16x8*>(&BC2[(size_t)n * 1024 + k8 * 8]) = cast8(s);
  } else if ((idx -= S3) < S4) {
    int node = idx / 24;
    int j = idx - node * 24;
    float4 v;
    int col;
    if (j < 8) {
      int t = ntype[node];
      v = *reinterpret_cast<const float4*>(&temb[t * 32 + j * 4]);
      col = j * 4;
    } else {
      int s = ntac[node] + 1;
      s = s < 0 ? 0 : (s > NTAC ? NTAC : s);
      v = *reinterpret_cast<const float4*>(&tacemb[s * 64 + (j - 8) * 4]);
      col = 32 + (j - 8) * 4;
    }
    short4v o = {f2bf(v.x), f2bf(v.y), f2bf(v.z), f2bf(v.w)};
    *reinterpret_cast<short4v*>(&A1[(size_t)node * 192 + 96 + col]) = o;
  } else if ((idx -= S4) < S5) {
    atomicAdd(&deg[dst[idx]], 1);
  } else if ((idx -= S5) < S6) {
    int i = idx;
    int b = batch[i];
    int bp = (i == 0) ? -1 : batch[i - 1];
    for (int g = bp + 1; g <= b; ++g) rstart[g] = i;
    if (i == N_NODES - 1)
      for (int g = b + 1; g <= NGRAPH; ++g) rstart[g] = N_NODES;
  } else if ((idx -= S6) < S7) {
    float4 z = {0.f, 0.f, 0.f, 0.f};
    *reinterpret_cast<float4*>(&COEF[(size_t)idx * 4]) = z;
  } else if ((idx -= S7) < S8) {
    float4 z = {0.f, 0.f, 0.f, 0.f};
    *reinterpret_cast<float4*>(&PX[(size_t)idx * 4]) = z;
  }
}

// ---------------- CSR build: exclusive scan ----------------
__global__ __launch_bounds__(1024) void k_scan(const int* __restrict__ deg,
                                               int* __restrict__ rowstart) {
  __shared__ int partial[1024];
  const int t = threadIdx.x;
  const int CH = (N_NODES + 1023) / 1024;  // 20
  int s = 0;
  for (int i = 0; i < CH; ++i) {
    int idx = t * CH + i;
    if (idx < N_NODES) s += deg[idx];
  }
  partial[t] = s;
  __syncthreads();
  for (int off = 1; off < 1024; off <<= 1) {
    int v = (t >= off) ? partial[t - off] : 0;
    __syncthreads();
    partial[t] += v;
    __syncthreads();
  }
  int run = (t == 0) ? 0 : partial[t - 1];
  for (int i = 0; i < CH; ++i) {
    int idx = t * CH + i;
    if (idx < N_NODES) { rowstart[idx] = run; run += deg[idx]; }
  }
  if (t == 1023) rowstart[N_NODES] = run;
}

// ---- scatter: CSR slots via atomicSub(DEG) + coef atomics -------------------
__global__ void k_scatter(const int* __restrict__ src, const int* __restrict__ dst,
                          const int* __restrict__ rows, int* __restrict__ deg,
                          int* __restrict__ esrc, const int* __restrict__ batch,
                          const int* __restrict__ rstart,
                          float* __restrict__ COEF) {
  int idx = blockIdx.x * 256 + threadIdx.x;
  if (idx >= N_EDGES) return;
  int d = dst[idx];
  int old = atomicSub(&deg[d], 1);
  int p = rows[d + 1] - old;
  int sj = src[idx];
  esrc[p] = sj;
  int g = batch[d];
  float invd = 1.0f / (float)max(rows[d + 1] - rows[d], 1);
  float invg = 1.0f / (float)max(rstart[g + 1] - rstart[g], 1);
  atomicAdd(&COEF[(size_t)g * N_NODES + sj], invd * invg);
}

// ---------------- mid: coef fp32->bf16 cast + gather96 ----------------
__global__ __launch_bounds__(256) void k_mid(
    const float* __restrict__ COEF, short* __restrict__ COEFB,
    const int* __restrict__ rowstart, const int* __restrict__ esrc,
    short* __restrict__ A1) {
  int idx = blockIdx.x * 256 + threadIdx.x;
  const int SC = NGRAPH * N_NODES / 8;   // 640000 cast octs
  if (idx < SC) {
    int r = idx / 2500, k8 = (idx - r * 2500) * 8;
    *reinterpret_cast<bf16x8*>(&COEFB[(size_t)r * N_NODES + k8]) =
        cast8(&COEF[(size_t)r * N_NODES + k8]);
    return;
  }
  idx -= SC;
  if (idx >= N_NODES * 24) return;
  int node = idx / 24;
  int c = (idx - node * 24) * 4;
  const int s0 = rowstart[node], s1 = rowstart[node + 1];
  float a0 = 0.f, a1 = 0.f, a2 = 0.f, a3 = 0.f;
  for (int i = s0; i < s1; ++i) {
    int nbr = esrc[i];
    short4v v = *reinterpret_cast<const short4v*>(&A1[(size_t)nbr * 192 + 96 + c]);
    a0 += bf2f(v[0]); a1 += bf2f(v[1]); a2 += bf2f(v[2]); a3 += bf2f(v[3]);
  }
  const float inv = 1.0f / fmaxf((float)(s1 - s0), 1.0f);
  short4v o = {f2bf(a0 * inv), f2bf(a1 * inv), f2bf(a2 * inv), f2bf(a3 * inv)};
  *reinterpret_cast<short4v*>(&A1[(size_t)node * 192 + c]) = o;
}

// ---------------- layer-1 GEMM: x1 = relu(A1 @ BC1^T + b1l) ----
// writes X1T[col][node] ([512][20000] bf16) AND accumulates per-graph x-pool
// partial sums into PX[256][512] (fp32 atomics) from the LDS tile.
__global__ __launch_bounds__(256) void k_gemm_l1(
    const short* __restrict__ A, const short* __restrict__ B,
    const float* __restrict__ bias, const int* __restrict__ batch,
    short* __restrict__ X1T, float* __restrict__ PX, int nxp) {
  constexpr int K = 192;
  __shared__ short smem[32768];   // 64 KB
  __shared__ int bsh[128];
  const int lin = blockIdx.x;
  const int pnl = (lin & 7) + ((lin >> 5) << 3);
  const int cbk = (lin >> 3) & 3;
  if (pnl >= nxp) return;
  const int m0 = pnl * 128, n0 = cbk * 128;
  const int t = threadIdx.x;
  const int l = t & 63, wid = t >> 6;
  const int wr = (wid >> 1) * 64, wc = (wid & 1) * 64;
  const int fr = l & 15, fs = l >> 4;

  f32x4 acc[4][4];
#pragma unroll
  for (int a = 0; a < 4; ++a)
#pragma unroll
    for (int b = 0; b < 4; ++b) acc[a][b] = (f32x4){0.f, 0.f, 0.f, 0.f};

  const int idx0 = t, r0 = idx0 >> 2, sp0 = idx0 & 3;
  const int sl0 = (sp0 - (r0 >> 1)) & 3;
  const int idx1 = t + 256, r1 = idx1 >> 2, sp1 = idx1 & 3;
  const int sl1 = (sp1 - (r1 >> 1)) & 3;
  int rowA0 = m0 + r0; rowA0 = rowA0 < N_NODES ? rowA0 : N_NODES - 1;
  int rowA1 = m0 + r1; rowA1 = rowA1 < N_NODES ? rowA1 : N_NODES - 1;
  const short* Ap0 = A + (size_t)rowA0 * K + sl0 * 8;
  const short* Ap1 = A + (size_t)rowA1 * K + sl1 * 8;
  const short* Bp0 = B + (size_t)(n0 + r0) * K + sl0 * 8;
  const short* Bp1 = B + (size_t)(n0 + r1) * K + sl1 * 8;
  constexpr int NK = K / 32;   // 6

#define STAGE1(bo, k0)                                 \
  gload16(Ap0 + (k0), &smem[(bo) + idx0 * 8]);         \
  gload16(Bp0 + (k0), &smem[(bo) + 4096 + idx0 * 8]);  \
  gload16(Ap1 + (k0), &smem[(bo) + idx1 * 8]);         \
  gload16(Bp1 + (k0), &smem[(bo) + 4096 + idx1 * 8]);

#define COMPUTE1(bo) {                                                             \
  bf16x8 av[4], bv[4];                                                             \
  _Pragma("unroll")                                                                \
  for (int mi = 0; mi < 4; ++mi) {                                                 \
    const int r = wr + mi * 16 + fr;                                               \
    av[mi] = *reinterpret_cast<const bf16x8*>(                                     \
        &smem[(bo) + r * 32 + ((fs + (r >> 1)) & 3) * 8]);                         \
  }                                                                                \
  _Pragma("unroll")                                                                \
  for (int ni = 0; ni < 4; ++ni) {                                                 \
    const int r = wc + ni * 16 + fr;                                               \
    bv[ni] = *reinterpret_cast<const bf16x8*>(                                     \
        &smem[(bo) + 4096 + r * 32 + ((fs + (r >> 1)) & 3) * 8]);                  \
  }                                                                                \
  _Pragma("unroll")                                                                \
  for (int mi = 0; mi < 4; ++mi)                                                   \
    _Pragma("unroll")                                                              \
    for (int ni = 0; ni < 4; ++ni)                                                 \
      acc[mi][ni] = __builtin_amdgcn_mfma_f32_16x16x32_bf16(av[mi], bv[ni],        \
                                                            acc[mi][ni], 0, 0, 0); }

  STAGE1(0, 0)
  STAGE1(8192, 32)
  STAGE1(16384, 64)
#pragma unroll
  for (int k = 0; k < NK; ++k) {
    if (k + 2 <= NK - 1)      { asm volatile("s_waitcnt vmcnt(8)" ::: "memory"); }
    else if (k + 1 <= NK - 1) { asm volatile("s_waitcnt vmcnt(4)" ::: "memory"); }
    else                      { asm volatile("s_waitcnt vmcnt(0)" ::: "memory"); }
    __builtin_amdgcn_s_barrier();
    if (k + 3 < NK) { STAGE1(((k + 3) & 3) * 8192, (k + 3) * 32) }
    COMPUTE1((k & 3) * 8192)
  }
#undef STAGE1
#undef COMPUTE1

  // transposed epilogue: smem[col][node] stride 136
  __syncthreads();
  if (t < 128) {
    int node = m0 + t;
    bsh[t] = batch[node < N_NODES ? node : N_NODES - 1];
  }
#pragma unroll
  for (int ni = 0; ni < 4; ++ni) {
    const int colL = wc + ni * 16 + fr;
    const float bb = bias[n0 + colL];
#pragma unroll
    for (int mi = 0; mi < 4; ++mi) {
      const f32x4 c = acc[mi][ni];
#pragma unroll
      for (int i = 0; i < 4; ++i) {
        const int rowL = wr + mi * 16 + fs * 4 + i;
        smem[colL * 136 + rowL] = f2bf(fmaxf(c[i] + bb, 0.f));
      }
    }
  }
  __syncthreads();
  // coalesced X1T rows
#pragma unroll
  for (int q = 0; q < 8; ++q) {
    const int it = q * 256 + t;
    const int cr = it >> 4, n8 = (it & 15) << 3;
    if (m0 + n8 < N_NODES)
      *reinterpret_cast<bf16x8*>(&X1T[(size_t)(n0 + cr) * N_NODES + m0 + n8]) =
          *reinterpret_cast<const bf16x8*>(&smem[cr * 136 + n8]);
  }
  // x-pool partial sums: thread t -> col t>>1, node half t&1 (64 nodes)
  {
    const int colp = t >> 1, hf = t & 1;
    float run = 0.f;
    int curg = -1;
    for (int i = 0; i < 64; ++i) {
      const int node = m0 + hf * 64 + i;
      if (node >= N_NODES) break;
      const int g = bsh[hf * 64 + i];
      const float v = bf2f(smem[colp * 136 + hf * 64 + i]);
      if (g != curg) {
        if (curg >= 0) atomicAdd(&PX[(size_t)curg * HD + n0 + colp], run);
        curg = g; run = v;
      } else {
        run += v;
      }
    }
    if (curg >= 0) atomicAdd(&PX[(size_t)curg * HD + n0 + colp], run);
  }
}

// ---- big GEMM: CP[ch] = COEFB[256][20000] @ X1T[512][20000]^T chunk ----------
// XCD-chunk mapping: all 8 blocks (2 panels x 4 sibs) of one K-chunk share
// blockIdx.x%8 (one XCD L2). grid 256 (8 lanes x 32 slots), chunk<25 guard.
__global__ __launch_bounds__(256) void k_bigemm(
    const short* __restrict__ A,   // COEFB [256][20000]
    const short* __restrict__ B,   // X1T   [512][20000]
    float* __restrict__ CP) {
  __shared__ short smem[32768];
  const int x = blockIdx.x & 7;          // XCD lane
  const int slot = blockIdx.x >> 3;      // 0..31
  const int chunk = x + 8 * (slot >> 3);
  if (chunk >= NC) return;
  const int sub = slot & 7;
  const int panel = sub >> 2, sib = sub & 3;
  const int m0 = panel * 128, n0 = sib * 128;
  const int kb = chunk * KCH;
  const int t = threadIdx.x;
  const int l = t & 63, wid = t >> 6;
  const int wr = (wid >> 1) * 64, wc = (wid & 1) * 64;
  const int fr = l & 15, fs = l >> 4;

  f32x4 acc[4][4];
#pragma unroll
  for (int a = 0; a < 4; ++a)
#pragma unroll
    for (int b = 0; b < 4; ++b) acc[a][b] = (f32x4){0.f, 0.f, 0.f, 0.f};

  const int idx0 = t, r0 = idx0 >> 2, sp0 = idx0 & 3;
  const int sl0 = (sp0 - (r0 >> 1)) & 3;
  const int idx1 = t + 256, r1 = idx1 >> 2, sp1 = idx1 & 3;
  const int sl1 = (sp1 - (r1 >> 1)) & 3;
  const short* Ap0 = A + (size_t)(m0 + r0) * N_NODES + kb + sl0 * 8;
  const short* Ap1 = A + (size_t)(m0 + r1) * N_NODES + kb + sl1 * 8;
  const short* Bp0 = B + (size_t)(n0 + r0) * N_NODES + kb + sl0 * 8;
  const short* Bp1 = B + (size_t)(n0 + r1) * N_NODES + kb + sl1 * 8;
  constexpr int NK = KCH / 32;   // 25

#define STAGE2(bo, k0)                                 \
  gload16(Ap0 + (k0), &smem[(bo) + idx0 * 8]);         \
  gload16(Bp0 + (k0), &smem[(bo) + 4096 + idx0 * 8]);  \
  gload16(Ap1 + (k0), &smem[(bo) + idx1 * 8]);         \
  gload16(Bp1 + (k0), &smem[(bo) + 4096 + idx1 * 8]);

#define COMPUTE2(bo) {                                                             \
  bf16x8 av[4], bv[4];                                                             \
  _Pragma("unroll")                                                                \
  for (int mi = 0; mi < 4; ++mi) {                                                 \
    const int r = wr + mi * 16 + fr;                                               \
    av[mi] = *reinterpret_cast<const bf16x8*>(                                     \
        &smem[(bo) + r * 32 + ((fs + (r >> 1)) & 3) * 8]);                         \
  }                                                                                \
  _Pragma("unroll")                                                                \
  for (int ni = 0; ni < 4; ++ni) {                                                 \
    const int r = wc + ni * 16 + fr;                                               \
    bv[ni] = *reinterpret_cast<const bf16x8*>(                                     \
        &smem[(bo) + 4096 + r * 32 + ((fs + (r >> 1)) & 3) * 8]);                  \
  }                                                                                \
  _Pragma("unroll")                                                                \
  for (int mi = 0; mi < 4; ++mi)                                                   \
    _Pragma("unroll")                                                              \
    for (int ni = 0; ni < 4; ++ni)                                                 \
      acc[mi][ni] = __builtin_amdgcn_mfma_f32_16x16x32_bf16(av[mi], bv[ni],        \
                                                            acc[mi][ni], 0, 0, 0); }

  STAGE2(0, 0)
  STAGE2(8192, 32)
  STAGE2(16384, 64)
  for (int k = 0; k < NK; ++k) {
    if (k + 2 <= NK - 1)      { asm volatile("s_waitcnt vmcnt(8)" ::: "memory"); }
    else if (k + 1 <= NK - 1) { asm volatile("s_waitcnt vmcnt(4)" ::: "memory"); }
    else                      { asm volatile("s_waitcnt vmcnt(0)" ::: "memory"); }
    __builtin_amdgcn_s_barrier();
    if (k + 3 < NK) { STAGE2(((k + 3) & 3) * 8192, (k + 3) * 32) }
    COMPUTE2((k & 3) * 8192)
  }
#undef STAGE2
#undef COMPUTE2

  // fp32 epilogue via LDS, two 64-row halves
  __syncthreads();
  float* smemf = reinterpret_cast<float*>(smem);
  for (int half = 0; half < 2; ++half) {
    if (wr == half * 64) {
#pragma unroll
      for (int ni = 0; ni < 4; ++ni) {
        const int colL = wc + ni * 16 + fr;
#pragma unroll
        for (int mi = 0; mi < 4; ++mi) {
          const f32x4 c = acc[mi][ni];
#pragma unroll
          for (int i = 0; i < 4; ++i) {
            const int row = mi * 16 + fs * 4 + i;   // 0..63 within half
            smemf[row * 132 + colL] = c[i];
          }
        }
      }
    }
    __syncthreads();
#pragma unroll
    for (int q = 0; q < 8; ++q) {
      const int it = q * 256 + t;
      const int row = it >> 5, c4 = (it & 31) * 4;
      *reinterpret_cast<f32x4*>(
          &CP[((size_t)chunk * 256 + m0 + half * 64 + row) * 512 + n0 + c4]) =
          *reinterpret_cast<const f32x4*>(&smemf[row * 132 + c4]);
    }
    __syncthreads();
  }
}

// ---- reduce: PB[g][0:512] = sum_ch CP (agg), PB[g][512:1024] = PX * invg ----
__global__ __launch_bounds__(256) void k_redP(const float* __restrict__ CP,
                                              const float* __restrict__ PX,
                                              const int* __restrict__ rstart,
                                              short* __restrict__ PB) {
  int it = blockIdx.x * 256 + threadIdx.x;    // 65536 quad-items
  if (it < 32768) {
    int g = it >> 7, c4 = (it & 127) * 4;
    f32x4 s = (f32x4){0.f, 0.f, 0.f, 0.f};
    for (int ch = 0; ch < NC; ++ch) {
      f32x4 v = *reinterpret_cast<const f32x4*>(
          &CP[((size_t)ch * 256 + g) * 512 + c4]);
      s[0] += v[0]; s[1] += v[1]; s[2] += v[2]; s[3] += v[3];
    }
    short4v o = {f2bf(s[0]), f2bf(s[1]), f2bf(s[2]), f2bf(s[3])};
    *reinterpret_cast<short4v*>(&PB[(size_t)g * 1024 + c4]) = o;
  } else {
    it -= 32768;
    int g = it >> 7, c4 = (it & 127) * 4;
    const float invg = 1.0f / fmaxf((float)(rstart[g + 1] - rstart[g]), 1.0f);
    f32x4 v = *reinterpret_cast<const f32x4*>(&PX[(size_t)g * HD + c4]);
    short4v o = {f2bf(v[0] * invg), f2bf(v[1] * invg),
                 f2bf(v[2] * invg), f2bf(v[3] * invg)};
    *reinterpret_cast<short4v*>(&PB[(size_t)g * 1024 + 512 + c4]) = o;
  }
}

// ---------------- classifier MFMA GEMM: C[256,N] = A[256,K] @ B[N,K]^T + bias -
template<int K, bool RELU, bool F32OUT>
__device__ __forceinline__ void cls_gemm(
    const short* __restrict__ A, const short* __restrict__ B,
    const float* __restrict__ bias,
    short* __restrict__ outS, int ostride, float* __restrict__ outF) {
  __shared__ short smem[32768];
  const int bx = blockIdx.x;
  const int m0 = (bx & 1) * 128;
  const int n0 = (bx >> 1) * 128;
  const int t = threadIdx.x;
  const int l = t & 63, wid = t >> 6;
  const int wr = (wid >> 1) * 64, wc = (wid & 1) * 64;
  const int fr = l & 15, fs = l >> 4;

  f32x4 acc[4][4];
#pragma unroll
  for (int a = 0; a < 4; ++a)
#pragma unroll
    for (int b = 0; b < 4; ++b) acc[a][b] = (f32x4){0.f, 0.f, 0.f, 0.f};

  const int idx0 = t, r0 = idx0 >> 2, sp0 = idx0 & 3;
  const int sl0 = (sp0 - (r0 >> 1)) & 3;
  const int idx1 = t + 256, r1 = idx1 >> 2, sp1 = idx1 & 3;
  const int sl1 = (sp1 - (r1 >> 1)) & 3;
  const short* Ap0 = A + (size_t)(m0 + r0) * K + sl0 * 8;
  const short* Ap1 = A + (size_t)(m0 + r1) * K + sl1 * 8;
  const short* Bp0 = B + (size_t)(n0 + r0) * K + sl0 * 8;
  const short* Bp1 = B + (size_t)(n0 + r1) * K + sl1 * 8;
  constexpr int NK = K / 32;

#define STAGE3(bo, k0)                                 \
  gload16(Ap0 + (k0), &smem[(bo) + idx0 * 8]);         \
  gload16(Bp0 + (k0), &smem[(bo) + 4096 + idx0 * 8]);  \
  gload16(Ap1 + (k0), &smem[(bo) + idx1 * 8]);         \
  gload16(Bp1 + (k0), &smem[(bo) + 4096 + idx1 * 8]);

#define COMPUTE3(bo) {                                                             \
  bf16x8 av[4], bv[4];                                                             \
  _Pragma("unroll")                                                                \
  for (int mi = 0; mi < 4; ++mi) {                                                 \
    const int r = wr + mi * 16 + fr;                                               \
    av[mi] = *reinterpret_cast<const bf16x8*>(                                     \
        &smem[(bo) + r * 32 + ((fs + (r >> 1)) & 3) * 8]);                         \
  }                                                                                \
  _Pragma("unroll")                                                                \
  for (int ni = 0; ni < 4; ++ni) {                                                 \
    const int r = wc + ni * 16 + fr;                                               \
    bv[ni] = *reinterpret_cast<const bf16x8*>(                                     \
        &smem[(bo) + 4096 + r * 32 + ((fs + (r >> 1)) & 3) * 8]);                  \
  }                                                                                \
  _Pragma("unroll")                                                                \
  for (int mi = 0; mi < 4; ++mi)                                                   \
    _Pragma("unroll")                                                              \
    for (int ni = 0; ni < 4; ++ni)                                                 \
      acc[mi][ni] = __builtin_amdgcn_mfma_f32_16x16x32_bf16(av[mi], bv[ni],        \
                                                            acc[mi][ni], 0, 0, 0); }

  STAGE3(0, 0)
  STAGE3(8192, 32)
  STAGE3(16384, 64)
  for (int k = 0; k < NK; ++k) {
    if (k + 2 <= NK - 1)      { asm volatile("s_waitcnt vmcnt(8)" ::: "memory"); }
    else if (k + 1 <= NK - 1) { asm volatile("s_waitcnt vmcnt(4)" ::: "memory"); }
    else                      { asm volatile("s_waitcnt vmcnt(0)" ::: "memory"); }
    __builtin_amdgcn_s_barrier();
    if (k + 3 < NK) { STAGE3(((k + 3) & 3) * 8192, (k + 3) * 32) }
    COMPUTE3((k & 3) * 8192)
  }
#undef STAGE3
#undef COMPUTE3

  __syncthreads();
  if constexpr (!F32OUT) {
#pragma unroll
    for (int ni = 0; ni < 4; ++ni) {
      const int colL = wc + ni * 16 + fr;
      const float bb = bias[n0 + colL];
#pragma unroll
      for (int mi = 0; mi < 4; ++mi) {
        const f32x4 c = acc[mi][ni];
#pragma unroll
        for (int i = 0; i < 4; ++i) {
          const int rowL = wr + mi * 16 + fs * 4 + i;
          float v = c[i] + bb;
          if (RELU) v = fmaxf(v, 0.f);
          smem[rowL * 136 + colL] = f2bf(v);
        }
      }
    }
    __syncthreads();
#pragma unroll
    for (int pz = 0; pz < 8; ++pz) {
      const int idx = pz * 256 + t;
      const int row = idx >> 4, c8 = (idx & 15) << 3;
      *reinterpret_cast<bf16x8*>(&outS[(size_t)(m0 + row) * ostride + n0 + c8]) =
          *reinterpret_cast<const bf16x8*>(&smem[row * 136 + c8]);
    }
  } else {
    float* smemf = reinterpret_cast<float*>(smem);
    for (int half = 0; half < 2; ++half) {
      if (wr == half * 64) {
#pragma unroll
        for (int ni = 0; ni < 4; ++ni) {
          const int colL = wc + ni * 16 + fr;
          const float bb = bias[n0 + colL];
#pragma unroll
          for (int mi = 0; mi < 4; ++mi) {
            const f32x4 c = acc[mi][ni];
#pragma unroll
            for (int i = 0; i < 4; ++i) {
              const int row = mi * 16 + fs * 4 + i;
              smemf[row * 132 + colL] = c[i] + bb;
            }
          }
        }
      }
      __syncthreads();
#pragma unroll
      for (int q = 0; q < 8; ++q) {
        const int it = q * 256 + t;
        const int row = it >> 5, c4 = (it & 31) * 4;
        if (n0 + c4 < NTAC)
          *reinterpret_cast<f32x4*>(
              &outF[(size_t)(m0 + half * 64 + row) * NTAC + n0 + c4]) =
              *reinterpret_cast<const f32x4*>(&smemf[row * 132 + c4]);
      }
      __syncthreads();
    }
  }
}

__global__ __launch_bounds__(256) void k_cls1(    // GRB = PB @ BC2^T + b2l
    const short* __restrict__ A, const short* __restrict__ B,
    const float* __restrict__ bias, short* __restrict__ outS) {
  cls_gemm<1024, false, false>(A, B, bias, outS, 512, nullptr);
}
__global__ __launch_bounds__(256) void k_cls2(    // HSB = relu(GRB @ Wc1B^T + bc1)
    const short* __restrict__ A, const short* __restrict__ B,
    const float* __restrict__ bias, short* __restrict__ outS) {
  cls_gemm<512, true, false>(A, B, bias, outS, 512, nullptr);
}
__global__ __launch_bounds__(256) void k_cls3(    // out = HSB @ Wc2B^T + bc2 (fp32)
    const short* __restrict__ A, const short* __restrict__ B,
    const float* __restrict__ bias, float* __restrict__ outF) {
  cls_gemm<512, false, true>(A, B, bias, nullptr, 0, outF);
}

extern "C" void kernel_launch(void* const* d_in, const int* in_sizes, int n_in,
                              void* d_out, int out_size, void* d_ws, size_t ws_size,
                              hipStream_t stream) {
  const int*   node_type = (const int*)d_in[0];
  const int*   node_tac  = (const int*)d_in[1];
  const int*   edge      = (const int*)d_in[2];
  const int*   batch     = (const int*)d_in[3];
  const float* temb      = (const float*)d_in[4];
  const float* tacemb    = (const float*)d_in[5];
  const float* W1l       = (const float*)d_in[6];
  const float* b1l       = (const float*)d_in[7];
  const float* W1r       = (const float*)d_in[8];
  const float* W2l       = (const float*)d_in[9];
  const float* b2l       = (const float*)d_in[10];
  const float* W2r       = (const float*)d_in[11];
  const float* Wc1       = (const float*)d_in[12];
  const float* bc1       = (const float*)d_in[13];
  const float* Wc2       = (const float*)d_in[14];
  const float* bc2       = (const float*)d_in[15];
  const int* src = edge;
  const int* dst = edge + N_EDGES;

  // ---- workspace layout (all blocks 16B-aligned) ----
  char* p = (char*)d_ws;
  int*   DEG    = (int*)p;    p += N_NODES * 4;                 // zeroed (memset)
  int*   ROWS   = (int*)p;    p += (N_NODES + 4) * 4;
  int*   RSTART = (int*)p;    p += (NGRAPH + 4) * 4;
  int*   ESRC   = (int*)p;    p += N_EDGES * 4;
  short* A1     = (short*)p;  p += (size_t)N_NODES * 192 * 2;   // [agg1 | x]
  short* X1T    = (short*)p;  p += (size_t)HD * N_NODES * 2;    // x1 transposed
  float* COEF   = (float*)p;  p += (size_t)NGRAPH * N_NODES * 4;
  short* COEFB  = (short*)p;  p += (size_t)NGRAPH * N_NODES * 2;
  float* PX     = (float*)p;  p += NGRAPH * HD * 4;             // zeroed by front
  float* CP     = (float*)p;  p += (size_t)NC * 256 * 512 * 4;
  short* PB     = (short*)p;  p += NGRAPH * 1024 * 2;
  short* GRB    = (short*)p;  p += NGRAPH * HD * 2;
  short* HSB    = (short*)p;  p += NGRAPH * HD * 2;
  short* BC1    = (short*)p;  p += HD * 192 * 2;
  short* BC2    = (short*)p;  p += HD * 1024 * 2;
  short* WC1B   = (short*)p;  p += HD * HD * 2;
  short* WC2B   = (short*)p;  p += (size_t)1024 * HD * 2;       // padded to 1024 rows

  hipMemsetAsync(DEG, 0, N_NODES * 4, stream);

  const int front_items = HD * HD / 8 + NTAC * HD / 8 + HD * 192 / 8 +
                          HD * 1024 / 8 + N_NODES * 24 + N_EDGES + N_NODES +
                          NGRAPH * N_NODES / 4 + NGRAPH * HD / 4;
  k_front<<<(front_items + 255) / 256, 256, 0, stream>>>(
      Wc1, Wc2, WC1B, WC2B, W1l, W1r, BC1, W2l, W2r, BC2,
      node_type, node_tac, temb, tacemb, A1, dst, DEG, batch, RSTART, COEF, PX);

  k_scan<<<1, 1024, 0, stream>>>(DEG, ROWS);
  k_scatter<<<(N_EDGES + 255) / 256, 256, 0, stream>>>(
      src, dst, ROWS, DEG, ESRC, batch, RSTART, COEF);

  const int mid_items = NGRAPH * N_NODES / 8 + N_NODES * 24;
  k_mid<<<(mid_items + 255) / 256, 256, 0, stream>>>(COEF, COEFB, ROWS, ESRC, A1);

  const int NXP = (N_NODES + 127) / 128;          // 157 row panels
  k_gemm_l1<<<640, 256, 0, stream>>>(A1, BC1, b1l, batch, X1T, PX, NXP);

  k_bigemm<<<256, 256, 0, stream>>>(COEFB, X1T, CP);
  k_redP<<<256, 256, 0, stream>>>(CP, PX, RSTART, PB);
  k_cls1<<<8, 256, 0, stream>>>(PB, BC2, b2l, GRB);
  k_cls2<<<8, 256, 0, stream>>>(GRB, WC1B, bc1, HSB);
  k_cls3<<<16, 256, 0, stream>>>(HSB, WC2B, bc2, (float*)d_out);
}

// Round 15
// 198.643 us; speedup vs baseline: 1.0205x; 1.0205x over previous
//
#include <hip/hip_runtime.h>

#define N_NODES 20000
#define N_EDGES 320000
#define NGRAPH  256
#define NTAC    1000
#define HD      512
#define NC      25          // K-chunks for the big GEMM (20000 = 25 * 800)
#define KCH     800

typedef __attribute__((ext_vector_type(8))) short bf16x8;
typedef __attribute__((ext_vector_type(4))) short short4v;
typedef __attribute__((ext_vector_type(4))) float f32x4;

__device__ __forceinline__ short f2bf(float f) {      // RNE float->bf16
  union { float f; unsigned u; } v; v.f = f;
  unsigned r = v.u + 0x7FFFu + ((v.u >> 16) & 1u);
  return (short)(r >> 16);
}
__device__ __forceinline__ float bf2f(short s) {
  union { unsigned u; float f; } v;
  v.u = ((unsigned)(unsigned short)s) << 16;
  return v.f;
}
__device__ __forceinline__ bf16x8 cast8(const float* p) {
  float4 v0 = *reinterpret_cast<const float4*>(p);
  float4 v1 = *reinterpret_cast<const float4*>(p + 4);
  bf16x8 o;
  o[0] = f2bf(v0.x); o[1] = f2bf(v0.y); o[2] = f2bf(v0.z); o[3] = f2bf(v0.w);
  o[4] = f2bf(v1.x); o[5] = f2bf(v1.y); o[6] = f2bf(v1.z); o[7] = f2bf(v1.w);
  return o;
}
__device__ __forceinline__ void gload16(const void* g, void* l) {
  __builtin_amdgcn_global_load_lds((const __attribute__((address_space(1))) void*)g,
                                   (__attribute__((address_space(3))) void*)l,
                                   16, 0, 0);
}

// ---- fused front: weight casts + embed + degree + gbounds + zero(COEFB, PX) -
__global__ void k_front(const float* __restrict__ Wc1, const float* __restrict__ Wc2,
                        short* __restrict__ WC1B, short* __restrict__ WC2B,
                        const float* __restrict__ W1l, const float* __restrict__ W1r,
                        short* __restrict__ BC1,
                        const float* __restrict__ W2l, const float* __restrict__ W2r,
                        short* __restrict__ BC2,
                        const int* __restrict__ ntype, const int* __restrict__ ntac,
                        const float* __restrict__ temb, const float* __restrict__ tacemb,
                        short* __restrict__ A1,
                        const int* __restrict__ dst, int* __restrict__ deg,
                        const int* __restrict__ batch, int* __restrict__ rstart,
                        short* __restrict__ COEFB, float* __restrict__ PX) {
  int idx = blockIdx.x * 256 + threadIdx.x;
  const int S0 = HD * HD / 8;          // Wc1 cast (oct)
  const int S1 = NTAC * HD / 8;        // Wc2 cast (oct)
  const int S2 = HD * 192 / 8;         // BC1 (oct)
  const int S3 = HD * 1024 / 8;        // BC2 (oct)
  const int S4 = N_NODES * 24;         // embed
  const int S5 = N_EDGES;              // degree
  const int S6 = N_NODES;              // gbounds
  const int S7 = NGRAPH * N_NODES / 8; // zero COEFB bf16 (oct)
  const int S8 = NGRAPH * HD / 4;      // zero PX fp32 (quad)
  if (idx < S0) {
    *reinterpret_cast<bf16x8*>(&WC1B[idx * 8]) = cast8(&Wc1[idx * 8]);
  } else if ((idx -= S0) < S1) {
    *reinterpret_cast<bf16x8*>(&WC2B[idx * 8]) = cast8(&Wc2[idx * 8]);
  } else if ((idx -= S1) < S2) {
    int n = idx / 24, k8 = idx - n * 24;
    const float* s = (k8 < 12) ? &W1l[(size_t)n * 96 + k8 * 8]
                               : &W1r[(size_t)n * 96 + (k8 - 12) * 8];
    *reinterpret_cast<bf16x8*>(&BC1[(size_t)n * 192 + k8 * 8]) = cast8(s);
  } else if ((idx -= S2) < S3) {
    int n = idx >> 7, k8 = idx & 127;
    const float* s = (k8 < 64) ? &W2l[(size_t)n * 512 + k8 * 8]
                               : &W2r[(size_t)n * 512 + (k8 - 64) * 8];
    *reinterpret_cast<bf16x8*>(&BC2[(size_t)n * 1024 + k8 * 8]) = cast8(s);
  } else if ((idx -= S3) < S4) {
    int node = idx / 24;
    int j = idx - node * 24;
    float4 v;
    int col;
    if (j < 8) {
      int t = ntype[node];
      v = *reinterpret_cast<const float4*>(&temb[t * 32 + j * 4]);
      col = j * 4;
    } else {
      int s = ntac[node] + 1;
      s = s < 0 ? 0 : (s > NTAC ? NTAC : s);
      v = *reinterpret_cast<const float4*>(&tacemb[s * 64 + (j - 8) * 4]);
      col = 32 + (j - 8) * 4;
    }
    short4v o = {f2bf(v.x), f2bf(v.y), f2bf(v.z), f2bf(v.w)};
    *reinterpret_cast<short4v*>(&A1[(size_t)node * 192 + 96 + col]) = o;
  } else if ((idx -= S4) < S5) {
    atomicAdd(&deg[dst[idx]], 1);
  } else if ((idx -= S5) < S6) {
    int i = idx;
    int b = batch[i];
    int bp = (i == 0) ? -1 : batch[i - 1];
    for (int g = bp + 1; g <= b; ++g) rstart[g] = i;
    if (i == N_NODES - 1)
      for (int g = b + 1; g <= NGRAPH; ++g) rstart[g] = N_NODES;
  } else if ((idx -= S6) < S7) {
    bf16x8 z = {0, 0, 0, 0, 0, 0, 0, 0};
    *reinterpret_cast<bf16x8*>(&COEFB[(size_t)idx * 8]) = z;
  } else if ((idx -= S7) < S8) {
    float4 z = {0.f, 0.f, 0.f, 0.f};
    *reinterpret_cast<float4*>(&PX[(size_t)idx * 4]) = z;
  }
}

// ---------------- CSR build: exclusive scan ----------------
__global__ __launch_bounds__(1024) void k_scan(const int* __restrict__ deg,
                                               int* __restrict__ rowstart) {
  __shared__ int partial[1024];
  const int t = threadIdx.x;
  const int CH = (N_NODES + 1023) / 1024;  // 20
  int s = 0;
  for (int i = 0; i < CH; ++i) {
    int idx = t * CH + i;
    if (idx < N_NODES) s += deg[idx];
  }
  partial[t] = s;
  __syncthreads();
  for (int off = 1; off < 1024; off <<= 1) {
    int v = (t >= off) ? partial[t - off] : 0;
    __syncthreads();
    partial[t] += v;
    __syncthreads();
  }
  int run = (t == 0) ? 0 : partial[t - 1];
  for (int i = 0; i < CH; ++i) {
    int idx = t * CH + i;
    if (idx < N_NODES) { rowstart[idx] = run; run += deg[idx]; }
  }
  if (t == 1023) rowstart[N_NODES] = run;
}

// ---- scatter: CSR slots via atomicSub(DEG) + pk-bf16 coef atomics -----------
__global__ void k_scatter(const int* __restrict__ src, const int* __restrict__ dst,
                          const int* __restrict__ rows, int* __restrict__ deg,
                          int* __restrict__ esrc, const int* __restrict__ batch,
                          const int* __restrict__ rstart,
                          short* __restrict__ COEFB) {
  int idx = blockIdx.x * 256 + threadIdx.x;
  if (idx >= N_EDGES) return;
  int d = dst[idx];
  int old = atomicSub(&deg[d], 1);
  int p = rows[d + 1] - old;
  int sj = src[idx];
  esrc[p] = sj;
  int g = batch[d];
  float invd = 1.0f / (float)max(rows[d + 1] - rows[d], 1);
  float invg = 1.0f / (float)max(rstart[g + 1] - rstart[g], 1);
  const float v = invd * invg;
  // packed bf16 atomic add: lane = cell parity, other lane adds +0.0 (exact)
  size_t cell = (size_t)g * N_NODES + sj;
  short* pair = COEFB + (cell & ~(size_t)1);
  unsigned bv = (unsigned)(unsigned short)f2bf(v);
  unsigned packed = (cell & 1) ? (bv << 16) : bv;
  asm volatile("global_atomic_pk_add_bf16 %0, %1, off"
               :: "v"(pair), "v"(packed) : "memory");
}

// ---------------- mid: gather96 (agg1 half of A1) ----------------
__global__ __launch_bounds__(256) void k_mid(
    const int* __restrict__ rowstart, const int* __restrict__ esrc,
    short* __restrict__ A1) {
  int idx = blockIdx.x * 256 + threadIdx.x;
  if (idx >= N_NODES * 24) return;
  int node = idx / 24;
  int c = (idx - node * 24) * 4;
  const int s0 = rowstart[node], s1 = rowstart[node + 1];
  float a0 = 0.f, a1 = 0.f, a2 = 0.f, a3 = 0.f;
  for (int i = s0; i < s1; ++i) {
    int nbr = esrc[i];
    short4v v = *reinterpret_cast<const short4v*>(&A1[(size_t)nbr * 192 + 96 + c]);
    a0 += bf2f(v[0]); a1 += bf2f(v[1]); a2 += bf2f(v[2]); a3 += bf2f(v[3]);
  }
  const float inv = 1.0f / fmaxf((float)(s1 - s0), 1.0f);
  short4v o = {f2bf(a0 * inv), f2bf(a1 * inv), f2bf(a2 * inv), f2bf(a3 * inv)};
  *reinterpret_cast<short4v*>(&A1[(size_t)node * 192 + c]) = o;
}

// ---------------- layer-1 GEMM: x1 = relu(A1 @ BC1^T + b1l) ----
// writes X1T[col][node] ([512][20000] bf16) AND accumulates per-graph x-pool
// partial sums into PX[256][512] (fp32 atomics) from the LDS tile.
__global__ __launch_bounds__(256) void k_gemm_l1(
    const short* __restrict__ A, const short* __restrict__ B,
    const float* __restrict__ bias, const int* __restrict__ batch,
    short* __restrict__ X1T, float* __restrict__ PX, int nxp) {
  constexpr int K = 192;
  __shared__ short smem[32768];   // 64 KB
  __shared__ int bsh[128];
  const int lin = blockIdx.x;
  const int pnl = (lin & 7) + ((lin >> 5) << 3);
  const int cbk = (lin >> 3) & 3;
  if (pnl >= nxp) return;
  const int m0 = pnl * 128, n0 = cbk * 128;
  const int t = threadIdx.x;
  const int l = t & 63, wid = t >> 6;
  const int wr = (wid >> 1) * 64, wc = (wid & 1) * 64;
  const int fr = l & 15, fs = l >> 4;

  f32x4 acc[4][4];
#pragma unroll
  for (int a = 0; a < 4; ++a)
#pragma unroll
    for (int b = 0; b < 4; ++b) acc[a][b] = (f32x4){0.f, 0.f, 0.f, 0.f};

  const int idx0 = t, r0 = idx0 >> 2, sp0 = idx0 & 3;
  const int sl0 = (sp0 - (r0 >> 1)) & 3;
  const int idx1 = t + 256, r1 = idx1 >> 2, sp1 = idx1 & 3;
  const int sl1 = (sp1 - (r1 >> 1)) & 3;
  int rowA0 = m0 + r0; rowA0 = rowA0 < N_NODES ? rowA0 : N_NODES - 1;
  int rowA1 = m0 + r1; rowA1 = rowA1 < N_NODES ? rowA1 : N_NODES - 1;
  const short* Ap0 = A + (size_t)rowA0 * K + sl0 * 8;
  const short* Ap1 = A + (size_t)rowA1 * K + sl1 * 8;
  const short* Bp0 = B + (size_t)(n0 + r0) * K + sl0 * 8;
  const short* Bp1 = B + (size_t)(n0 + r1) * K + sl1 * 8;
  constexpr int NK = K / 32;   // 6

#define STAGE1(bo, k0)                                 \
  gload16(Ap0 + (k0), &smem[(bo) + idx0 * 8]);         \
  gload16(Bp0 + (k0), &smem[(bo) + 4096 + idx0 * 8]);  \
  gload16(Ap1 + (k0), &smem[(bo) + idx1 * 8]);         \
  gload16(Bp1 + (k0), &smem[(bo) + 4096 + idx1 * 8]);

#define COMPUTE1(bo) {                                                             \
  bf16x8 av[4], bv[4];                                                             \
  _Pragma("unroll")                                                                \
  for (int mi = 0; mi < 4; ++mi) {                                                 \
    const int r = wr + mi * 16 + fr;                                               \
    av[mi] = *reinterpret_cast<const bf16x8*>(                                     \
        &smem[(bo) + r * 32 + ((fs + (r >> 1)) & 3) * 8]);                         \
  }                                                                                \
  _Pragma("unroll")                                                                \
  for (int ni = 0; ni < 4; ++ni) {                                                 \
    const int r = wc + ni * 16 + fr;                                               \
    bv[ni] = *reinterpret_cast<const bf16x8*>(                                     \
        &smem[(bo) + 4096 + r * 32 + ((fs + (r >> 1)) & 3) * 8]);                  \
  }                                                                                \
  _Pragma("unroll")                                                                \
  for (int mi = 0; mi < 4; ++mi)                                                   \
    _Pragma("unroll")                                                              \
    for (int ni = 0; ni < 4; ++ni)                                                 \
      acc[mi][ni] = __builtin_amdgcn_mfma_f32_16x16x32_bf16(av[mi], bv[ni],        \
                                                            acc[mi][ni], 0, 0, 0); }

  STAGE1(0, 0)
  STAGE1(8192, 32)
  STAGE1(16384, 64)
#pragma unroll
  for (int k = 0; k < NK; ++k) {
    if (k + 2 <= NK - 1)      { asm volatile("s_waitcnt vmcnt(8)" ::: "memory"); }
    else if (k + 1 <= NK - 1) { asm volatile("s_waitcnt vmcnt(4)" ::: "memory"); }
    else                      { asm volatile("s_waitcnt vmcnt(0)" ::: "memory"); }
    __builtin_amdgcn_s_barrier();
    if (k + 3 < NK) { STAGE1(((k + 3) & 3) * 8192, (k + 3) * 32) }
    COMPUTE1((k & 3) * 8192)
  }
#undef STAGE1
#undef COMPUTE1

  // transposed epilogue: smem[col][node] stride 136
  __syncthreads();
  if (t < 128) {
    int node = m0 + t;
    bsh[t] = batch[node < N_NODES ? node : N_NODES - 1];
  }
#pragma unroll
  for (int ni = 0; ni < 4; ++ni) {
    const int colL = wc + ni * 16 + fr;
    const float bb = bias[n0 + colL];
#pragma unroll
    for (int mi = 0; mi < 4; ++mi) {
      const f32x4 c = acc[mi][ni];
#pragma unroll
      for (int i = 0; i < 4; ++i) {
        const int rowL = wr + mi * 16 + fs * 4 + i;
        smem[colL * 136 + rowL] = f2bf(fmaxf(c[i] + bb, 0.f));
      }
    }
  }
  __syncthreads();
  // coalesced X1T rows
#pragma unroll
  for (int q = 0; q < 8; ++q) {
    const int it = q * 256 + t;
    const int cr = it >> 4, n8 = (it & 15) << 3;
    if (m0 + n8 < N_NODES)
      *reinterpret_cast<bf16x8*>(&X1T[(size_t)(n0 + cr) * N_NODES + m0 + n8]) =
          *reinterpret_cast<const bf16x8*>(&smem[cr * 136 + n8]);
  }
  // x-pool partial sums: thread t -> col t>>1, node half t&1 (64 nodes)
  {
    const int colp = t >> 1, hf = t & 1;
    float run = 0.f;
    int curg = -1;
    for (int i = 0; i < 64; ++i) {
      const int node = m0 + hf * 64 + i;
      if (node >= N_NODES) break;
      const int g = bsh[hf * 64 + i];
      const float v = bf2f(smem[colp * 136 + hf * 64 + i]);
      if (g != curg) {
        if (curg >= 0) atomicAdd(&PX[(size_t)curg * HD + n0 + colp], run);
        curg = g; run = v;
      } else {
        run += v;
      }
    }
    if (curg >= 0) atomicAdd(&PX[(size_t)curg * HD + n0 + colp], run);
  }
}

// ---- big GEMM: CP[ch] = COEFB[256][20000] @ X1T[512][20000]^T chunk ----------
// XCD-chunk mapping: all 8 blocks (2 panels x 4 sibs) of one K-chunk share
// blockIdx.x%8 (one XCD L2). grid 256 (8 lanes x 32 slots), chunk<25 guard.
__global__ __launch_bounds__(256) void k_bigemm(
    const short* __restrict__ A,   // COEFB [256][20000]
    const short* __restrict__ B,   // X1T   [512][20000]
    float* __restrict__ CP) {
  __shared__ short smem[32768];
  const int x = blockIdx.x & 7;          // XCD lane
  const int slot = blockIdx.x >> 3;      // 0..31
  const int chunk = x + 8 * (slot >> 3);
  if (chunk >= NC) return;
  const int sub = slot & 7;
  const int panel = sub >> 2, sib = sub & 3;
  const int m0 = panel * 128, n0 = sib * 128;
  const int kb = chunk * KCH;
  const int t = threadIdx.x;
  const int l = t & 63, wid = t >> 6;
  const int wr = (wid >> 1) * 64, wc = (wid & 1) * 64;
  const int fr = l & 15, fs = l >> 4;

  f32x4 acc[4][4];
#pragma unroll
  for (int a = 0; a < 4; ++a)
#pragma unroll
    for (int b = 0; b < 4; ++b) acc[a][b] = (f32x4){0.f, 0.f, 0.f, 0.f};

  const int idx0 = t, r0 = idx0 >> 2, sp0 = idx0 & 3;
  const int sl0 = (sp0 - (r0 >> 1)) & 3;
  const int idx1 = t + 256, r1 = idx1 >> 2, sp1 = idx1 & 3;
  const int sl1 = (sp1 - (r1 >> 1)) & 3;
  const short* Ap0 = A + (size_t)(m0 + r0) * N_NODES + kb + sl0 * 8;
  const short* Ap1 = A + (size_t)(m0 + r1) * N_NODES + kb + sl1 * 8;
  const short* Bp0 = B + (size_t)(n0 + r0) * N_NODES + kb + sl0 * 8;
  const short* Bp1 = B + (size_t)(n0 + r1) * N_NODES + kb + sl1 * 8;
  constexpr int NK = KCH / 32;   // 25

#define STAGE2(bo, k0)                                 \
  gload16(Ap0 + (k0), &smem[(bo) + idx0 * 8]);         \
  gload16(Bp0 + (k0), &smem[(bo) + 4096 + idx0 * 8]);  \
  gload16(Ap1 + (k0), &smem[(bo) + idx1 * 8]);         \
  gload16(Bp1 + (k0), &smem[(bo) + 4096 + idx1 * 8]);

#define COMPUTE2(bo) {                                                             \
  bf16x8 av[4], bv[4];                                                             \
  _Pragma("unroll")                                                                \
  for (int mi = 0; mi < 4; ++mi) {                                                 \
    const int r = wr + mi * 16 + fr;                                               \
    av[mi] = *reinterpret_cast<const bf16x8*>(                                     \
        &smem[(bo) + r * 32 + ((fs + (r >> 1)) & 3) * 8]);                         \
  }                                                                                \
  _Pragma("unroll")                                                                \
  for (int ni = 0; ni < 4; ++ni) {                                                 \
    const int r = wc + ni * 16 + fr;                                               \
    bv[ni] = *reinterpret_cast<const bf16x8*>(                                     \
        &smem[(bo) + 4096 + r * 32 + ((fs + (r >> 1)) & 3) * 8]);                  \
  }                                                                                \
  _Pragma("unroll")                                                                \
  for (int mi = 0; mi < 4; ++mi)                                                   \
    _Pragma("unroll")                                                              \
    for (int ni = 0; ni < 4; ++ni)                                                 \
      acc[mi][ni] = __builtin_amdgcn_mfma_f32_16x16x32_bf16(av[mi], bv[ni],        \
                                                            acc[mi][ni], 0, 0, 0); }

  STAGE2(0, 0)
  STAGE2(8192, 32)
  STAGE2(16384, 64)
  for (int k = 0; k < NK; ++k) {
    if (k + 2 <= NK - 1)      { asm volatile("s_waitcnt vmcnt(8)" ::: "memory"); }
    else if (k + 1 <= NK - 1) { asm volatile("s_waitcnt vmcnt(4)" ::: "memory"); }
    else                      { asm volatile("s_waitcnt vmcnt(0)" ::: "memory"); }
    __builtin_amdgcn_s_barrier();
    if (k + 3 < NK) { STAGE2(((k + 3) & 3) * 8192, (k + 3) * 32) }
    COMPUTE2((k & 3) * 8192)
  }
#undef STAGE2
#undef COMPUTE2

  // fp32 epilogue via LDS, two 64-row halves
  __syncthreads();
  float* smemf = reinterpret_cast<float*>(smem);
  for (int half = 0; half < 2; ++half) {
    if (wr == half * 64) {
#pragma unroll
      for (int ni = 0; ni < 4; ++ni) {
        const int colL = wc + ni * 16 + fr;
#pragma unroll
        for (int mi = 0; mi < 4; ++mi) {
          const f32x4 c = acc[mi][ni];
#pragma unroll
          for (int i = 0; i < 4; ++i) {
            const int row = mi * 16 + fs * 4 + i;   // 0..63 within half
            smemf[row * 132 + colL] = c[i];
          }
        }
      }
    }
    __syncthreads();
#pragma unroll
    for (int q = 0; q < 8; ++q) {
      const int it = q * 256 + t;
      const int row = it >> 5, c4 = (it & 31) * 4;
      *reinterpret_cast<f32x4*>(
          &CP[((size_t)chunk * 256 + m0 + half * 64 + row) * 512 + n0 + c4]) =
          *reinterpret_cast<const f32x4*>(&smemf[row * 132 + c4]);
    }
    __syncthreads();
  }
}

// ---- reduce: PB[g][0:512] = sum_ch CP (agg), PB[g][512:1024] = PX * invg ----
__global__ __launch_bounds__(256) void k_redP(const float* __restrict__ CP,
                                              const float* __restrict__ PX,
                                              const int* __restrict__ rstart,
                                              short* __restrict__ PB) {
  int it = blockIdx.x * 256 + threadIdx.x;    // 65536 quad-items
  if (it < 32768) {
    int g = it >> 7, c4 = (it & 127) * 4;
    f32x4 s = (f32x4){0.f, 0.f, 0.f, 0.f};
    for (int ch = 0; ch < NC; ++ch) {
      f32x4 v = *reinterpret_cast<const f32x4*>(
          &CP[((size_t)ch * 256 + g) * 512 + c4]);
      s[0] += v[0]; s[1] += v[1]; s[2] += v[2]; s[3] += v[3];
    }
    short4v o = {f2bf(s[0]), f2bf(s[1]), f2bf(s[2]), f2bf(s[3])};
    *reinterpret_cast<short4v*>(&PB[(size_t)g * 1024 + c4]) = o;
  } else {
    it -= 32768;
    int g = it >> 7, c4 = (it & 127) * 4;
    const float invg = 1.0f / fmaxf((float)(rstart[g + 1] - rstart[g]), 1.0f);
    f32x4 v = *reinterpret_cast<const f32x4*>(&PX[(size_t)g * HD + c4]);
    short4v o = {f2bf(v[0] * invg), f2bf(v[1] * invg),
                 f2bf(v[2] * invg), f2bf(v[3] * invg)};
    *reinterpret_cast<short4v*>(&PB[(size_t)g * 1024 + 512 + c4]) = o;
  }
}

// ---------------- classifier MFMA GEMM: C[256,N] = A[256,K] @ B[N,K]^T + bias -
template<int K, bool RELU, bool F32OUT>
__device__ __forceinline__ void cls_gemm(
    const short* __restrict__ A, const short* __restrict__ B,
    const float* __restrict__ bias,
    short* __restrict__ outS, int ostride, float* __restrict__ outF) {
  __shared__ short smem[32768];
  const int bx = blockIdx.x;
  const int m0 = (bx & 1) * 128;
  const int n0 = (bx >> 1) * 128;
  const int t = threadIdx.x;
  const int l = t & 63, wid = t >> 6;
  const int wr = (wid >> 1) * 64, wc = (wid & 1) * 64;
  const int fr = l & 15, fs = l >> 4;

  f32x4 acc[4][4];
#pragma unroll
  for (int a = 0; a < 4; ++a)
#pragma unroll
    for (int b = 0; b < 4; ++b) acc[a][b] = (f32x4){0.f, 0.f, 0.f, 0.f};

  const int idx0 = t, r0 = idx0 >> 2, sp0 = idx0 & 3;
  const int sl0 = (sp0 - (r0 >> 1)) & 3;
  const int idx1 = t + 256, r1 = idx1 >> 2, sp1 = idx1 & 3;
  const int sl1 = (sp1 - (r1 >> 1)) & 3;
  const short* Ap0 = A + (size_t)(m0 + r0) * K + sl0 * 8;
  const short* Ap1 = A + (size_t)(m0 + r1) * K + sl1 * 8;
  const short* Bp0 = B + (size_t)(n0 + r0) * K + sl0 * 8;
  const short* Bp1 = B + (size_t)(n0 + r1) * K + sl1 * 8;
  constexpr int NK = K / 32;

#define STAGE3(bo, k0)                                 \
  gload16(Ap0 + (k0), &smem[(bo) + idx0 * 8]);         \
  gload16(Bp0 + (k0), &smem[(bo) + 4096 + idx0 * 8]);  \
  gload16(Ap1 + (k0), &smem[(bo) + idx1 * 8]);         \
  gload16(Bp1 + (k0), &smem[(bo) + 4096 + idx1 * 8]);

#define COMPUTE3(bo) {                                                             \
  bf16x8 av[4], bv[4];                                                             \
  _Pragma("unroll")                                                                \
  for (int mi = 0; mi < 4; ++mi) {                                                 \
    const int r = wr + mi * 16 + fr;                                               \
    av[mi] = *reinterpret_cast<const bf16x8*>(                                     \
        &smem[(bo) + r * 32 + ((fs + (r >> 1)) & 3) * 8]);                         \
  }                                                                                \
  _Pragma("unroll")                                                                \
  for (int ni = 0; ni < 4; ++ni) {                                                 \
    const int r = wc + ni * 16 + fr;                                               \
    bv[ni] = *reinterpret_cast<const bf16x8*>(                                     \
        &smem[(bo) + 4096 + r * 32 + ((fs + (r >> 1)) & 3) * 8]);                  \
  }                                                                                \
  _Pragma("unroll")                                                                \
  for (int mi = 0; mi < 4; ++mi)                                                   \
    _Pragma("unroll")                                                              \
    for (int ni = 0; ni < 4; ++ni)                                                 \
      acc[mi][ni] = __builtin_amdgcn_mfma_f32_16x16x32_bf16(av[mi], bv[ni],        \
                                                            acc[mi][ni], 0, 0, 0); }

  STAGE3(0, 0)
  STAGE3(8192, 32)
  STAGE3(16384, 64)
  for (int k = 0; k < NK; ++k) {
    if (k + 2 <= NK - 1)      { asm volatile("s_waitcnt vmcnt(8)" ::: "memory"); }
    else if (k + 1 <= NK - 1) { asm volatile("s_waitcnt vmcnt(4)" ::: "memory"); }
    else                      { asm volatile("s_waitcnt vmcnt(0)" ::: "memory"); }
    __builtin_amdgcn_s_barrier();
    if (k + 3 < NK) { STAGE3(((k + 3) & 3) * 8192, (k + 3) * 32) }
    COMPUTE3((k & 3) * 8192)
  }
#undef STAGE3
#undef COMPUTE3

  __syncthreads();
  if constexpr (!F32OUT) {
#pragma unroll
    for (int ni = 0; ni < 4; ++ni) {
      const int colL = wc + ni * 16 + fr;
      const float bb = bias[n0 + colL];
#pragma unroll
      for (int mi = 0; mi < 4; ++mi) {
        const f32x4 c = acc[mi][ni];
#pragma unroll
        for (int i = 0; i < 4; ++i) {
          const int rowL = wr + mi * 16 + fs * 4 + i;
          float v = c[i] + bb;
          if (RELU) v = fmaxf(v, 0.f);
          smem[rowL * 136 + colL] = f2bf(v);
        }
      }
    }
    __syncthreads();
#pragma unroll
    for (int pz = 0; pz < 8; ++pz) {
      const int idx = pz * 256 + t;
      const int row = idx >> 4, c8 = (idx & 15) << 3;
      *reinterpret_cast<bf16x8*>(&outS[(size_t)(m0 + row) * ostride + n0 + c8]) =
          *reinterpret_cast<const bf16x8*>(&smem[row * 136 + c8]);
    }
  } else {
    float* smemf = reinterpret_cast<float*>(smem);
    for (int half = 0; half < 2; ++half) {
      if (wr == half * 64) {
#pragma unroll
        for (int ni = 0; ni < 4; ++ni) {
          const int colL = wc + ni * 16 + fr;
          const float bb = bias[n0 + colL];
#pragma unroll
          for (int mi = 0; mi < 4; ++mi) {
            const f32x4 c = acc[mi][ni];
#pragma unroll
            for (int i = 0; i < 4; ++i) {
              const int row = mi * 16 + fs * 4 + i;
              smemf[row * 132 + colL] = c[i] + bb;
            }
          }
        }
      }
      __syncthreads();
#pragma unroll
      for (int q = 0; q < 8; ++q) {
        const int it = q * 256 + t;
        const int row = it >> 5, c4 = (it & 31) * 4;
        if (n0 + c4 < NTAC)
          *reinterpret_cast<f32x4*>(
              &outF[(size_t)(m0 + half * 64 + row) * NTAC + n0 + c4]) =
              *reinterpret_cast<const f32x4*>(&smemf[row * 132 + c4]);
      }
      __syncthreads();
    }
  }
}

__global__ __launch_bounds__(256) void k_cls1(    // GRB = PB @ BC2^T + b2l
    const short* __restrict__ A, const short* __restrict__ B,
    const float* __restrict__ bias, short* __restrict__ outS) {
  cls_gemm<1024, false, false>(A, B, bias, outS, 512, nullptr);
}
__global__ __launch_bounds__(256) void k_cls2(    // HSB = relu(GRB @ Wc1B^T + bc1)
    const short* __restrict__ A, const short* __restrict__ B,
    const float* __restrict__ bias, short* __restrict__ outS) {
  cls_gemm<512, true, false>(A, B, bias, outS, 512, nullptr);
}
__global__ __launch_bounds__(256) void k_cls3(    // out = HSB @ Wc2B^T + bc2 (fp32)
    const short* __restrict__ A, const short* __restrict__ B,
    const float* __restrict__ bias, float* __restrict__ outF) {
  cls_gemm<512, false, true>(A, B, bias, nullptr, 0, outF);
}

extern "C" void kernel_launch(void* const* d_in, const int* in_sizes, int n_in,
                              void* d_out, int out_size, void* d_ws, size_t ws_size,
                              hipStream_t stream) {
  const int*   node_type = (const int*)d_in[0];
  const int*   node_tac  = (const int*)d_in[1];
  const int*   edge      = (const int*)d_in[2];
  const int*   batch     = (const int*)d_in[3];
  const float* temb      = (const float*)d_in[4];
  const float* tacemb    = (const float*)d_in[5];
  const float* W1l       = (const float*)d_in[6];
  const float* b1l       = (const float*)d_in[7];
  const float* W1r       = (const float*)d_in[8];
  const float* W2l       = (const float*)d_in[9];
  const float* b2l       = (const float*)d_in[10];
  const float* W2r       = (const float*)d_in[11];
  const float* Wc1       = (const float*)d_in[12];
  const float* bc1       = (const float*)d_in[13];
  const float* Wc2       = (const float*)d_in[14];
  const float* bc2       = (const float*)d_in[15];
  const int* src = edge;
  const int* dst = edge + N_EDGES;

  // ---- workspace layout (all blocks 16B-aligned) ----
  char* p = (char*)d_ws;
  int*   DEG    = (int*)p;    p += N_NODES * 4;                 // zeroed (memset)
  int*   ROWS   = (int*)p;    p += (N_NODES + 4) * 4;
  int*   RSTART = (int*)p;    p += (NGRAPH + 4) * 4;
  int*   ESRC   = (int*)p;    p += N_EDGES * 4;
  short* A1     = (short*)p;  p += (size_t)N_NODES * 192 * 2;   // [agg1 | x]
  short* X1T    = (short*)p;  p += (size_t)HD * N_NODES * 2;    // x1 transposed
  short* COEFB  = (short*)p;  p += (size_t)NGRAPH * N_NODES * 2; // bf16 coef (zeroed)
  float* PX     = (float*)p;  p += NGRAPH * HD * 4;             // zeroed by front
  float* CP     = (float*)p;  p += (size_t)NC * 256 * 512 * 4;
  short* PB     = (short*)p;  p += NGRAPH * 1024 * 2;
  short* GRB    = (short*)p;  p += NGRAPH * HD * 2;
  short* HSB    = (short*)p;  p += NGRAPH * HD * 2;
  short* BC1    = (short*)p;  p += HD * 192 * 2;
  short* BC2    = (short*)p;  p += HD * 1024 * 2;
  short* WC1B   = (short*)p;  p += HD * HD * 2;
  short* WC2B   = (short*)p;  p += (size_t)1024 * HD * 2;       // padded to 1024 rows

  hipMemsetAsync(DEG, 0, N_NODES * 4, stream);

  const int front_items = HD * HD / 8 + NTAC * HD / 8 + HD * 192 / 8 +
                          HD * 1024 / 8 + N_NODES * 24 + N_EDGES + N_NODES +
                          NGRAPH * N_NODES / 8 + NGRAPH * HD / 4;
  k_front<<<(front_items + 255) / 256, 256, 0, stream>>>(
      Wc1, Wc2, WC1B, WC2B, W1l, W1r, BC1, W2l, W2r, BC2,
      node_type, node_tac, temb, tacemb, A1, dst, DEG, batch, RSTART, COEFB, PX);

  k_scan<<<1, 1024, 0, stream>>>(DEG, ROWS);
  k_scatter<<<(N_EDGES + 255) / 256, 256, 0, stream>>>(
      src, dst, ROWS, DEG, ESRC, batch, RSTART, COEFB);

  k_mid<<<(N_NODES * 24 + 255) / 256, 256, 0, stream>>>(ROWS, ESRC, A1);

  const int NXP = (N_NODES + 127) / 128;          // 157 row panels
  k_gemm_l1<<<640, 256, 0, stream>>>(A1, BC1, b1l, batch, X1T, PX, NXP);

  k_bigemm<<<256, 256, 0, stream>>>(COEFB, X1T, CP);
  k_redP<<<256, 256, 0, stream>>>(CP, PX, RSTART, PB);
  k_cls1<<<8, 256, 0, stream>>>(PB, BC2, b2l, GRB);
  k_cls2<<<8, 256, 0, stream>>>(GRB, WC1B, bc1, HSB);
  k_cls3<<<16, 256, 0, stream>>>(HSB, WC2B, bc2, (float*)d_out);
}